// Round 2
// baseline (3822.707 us; speedup 1.0000x reference)
//
#include <hip/hip_runtime.h>
#include <hip/hip_bf16.h>

#define DEVINL __device__ __forceinline__

constexpr int Cc  = 256;
constexpr int Hh  = 56;
constexpr int Ww  = 56;
constexpr int Tn  = 32 * 56 * 56;   // 100352 tokens
constexpr int HW  = Hh * Ww;        // 3136
constexpr int NB  = 8;              // batches per chunk
constexpr int NCHUNK = 32 / NB;     // 4 chunks
constexpr int MCH = NB * HW;        // 25088 rows per chunk

DEVINL unsigned short f2bf(float f) {
  __hip_bfloat16 h = __float2bfloat16(f);
  return *reinterpret_cast<unsigned short*>(&h);
}
DEVINL float bf2f(unsigned short u) {
  union { unsigned int i; float f; } v; v.i = (unsigned int)u << 16; return v.f;
}

// ------------- Kernel 1: depthwise 3x3 CPE + residual, NCHW -> token(t,c) f32 ---
__global__ __launch_bounds__(256) void cpe_kernel(const float* __restrict__ x,
    const float* __restrict__ cw, const float* __restrict__ cb,
    float* __restrict__ out)
{
  const int t = blockIdx.x;
  const int c = threadIdx.x;
  const int b = t / HW;
  const int s = t - b * HW;
  const int h = s / Ww;
  const int w = s - h * Ww;
  const float* xb = x + ((size_t)b * Cc + c) * HW;
  float acc = xb[h * Ww + w];            // residual (input itself)
  #pragma unroll
  for (int dh = -1; dh <= 1; ++dh) {
    const int h2 = h + dh;
    if (h2 < 0 || h2 >= Hh) continue;
    #pragma unroll
    for (int dw = -1; dw <= 1; ++dw) {
      const int w2 = w + dw;
      if (w2 < 0 || w2 >= Ww) continue;
      acc += cw[c * 9 + (dh + 1) * 3 + (dw + 1)] * xb[h2 * Ww + w2];
    }
  }
  out[(size_t)t * Cc + c] = acc + cb[c];
}

// ------------- Kernel 2: per-token LN stats (mean, rstd) over C=256 -------------
template<int BF>
__global__ __launch_bounds__(256) void stats_kernel(const void* __restrict__ inp,
    float* __restrict__ mu, float* __restrict__ rs)
{
  const int lane = threadIdx.x & 63;
  const size_t t = (size_t)blockIdx.x * 4 + (threadIdx.x >> 6);
  float v0, v1, v2, v3;
  if constexpr (BF == 0) {
    const float4 v = *reinterpret_cast<const float4*>(
        reinterpret_cast<const float*>(inp) + t * Cc + lane * 4);
    v0 = v.x; v1 = v.y; v2 = v.z; v3 = v.w;
  } else {
    const ushort4 v = *reinterpret_cast<const ushort4*>(
        reinterpret_cast<const unsigned short*>(inp) + t * Cc + lane * 4);
    v0 = bf2f(v.x); v1 = bf2f(v.y); v2 = bf2f(v.z); v3 = bf2f(v.w);
  }
  float s  = v0 + v1 + v2 + v3;
  float sq = v0 * v0 + v1 * v1 + v2 * v2 + v3 * v3;
  #pragma unroll
  for (int o = 32; o >= 1; o >>= 1) {
    s  += __shfl_xor(s, o);
    sq += __shfl_xor(sq, o);
  }
  if (lane == 0) {
    const float mean = s * (1.0f / Cc);
    const float var  = sq * (1.0f / Cc) - mean * mean;
    mu[t] = mean;
    rs[t] = rsqrtf(var + 1e-5f);
  }
}

// ------------- Tiled fp32 GEMM with optional fused-LN A-load + epilogues --------
// ATBF: A dtype 0=f32 1=bf16. LNF: normalize A rows on load.
// EPI 0: bf16 out +bias                       (QKV)
// EPI 1: bf16 out +bias +res(f32)             (proj + shortcut)
// EPI 2: bf16 out +bias, exact GELU           (fc1)
// EPI 3: f32 NCHW out +bias +res(bf16)        (fc2 + residual + transpose)
template<int ATBF, int LNF, int EPI>
__global__ __launch_bounds__(256) void gemm_kernel(
    const void* __restrict__ Ap, const float* __restrict__ Bw,
    const float* __restrict__ bias, const float* __restrict__ lnw,
    const float* __restrict__ lnb, const float* __restrict__ mu,
    const float* __restrict__ rs, const void* __restrict__ resp,
    void* __restrict__ outp, int K, int N, int row0)
{
  __shared__ float As[16][68];
  __shared__ float Bs[16][68];
  const int tid = threadIdx.x;
  const int tx = tid & 15, ty = tid >> 4;
  const int bm = blockIdx.x * 64;
  const int bn = blockIdx.y * 64;
  const int lr = tid >> 2;          // A row within tile (0..63)
  const int lk = (tid & 3) * 4;     // A k offset (0,4,8,12)
  const int br = tid >> 4;          // B row (0..15)
  const int bc = (tid & 15) * 4;    // B col offset
  const int arow = bm + lr;
  float acc[4][4] = {};

  float lnm = 0.f, lnr = 0.f;
  if constexpr (LNF) { lnm = mu[arow]; lnr = rs[arow]; }

  for (int kk = 0; kk < K; kk += 16) {
    float a0, a1, a2, a3;
    if constexpr (ATBF == 0) {
      const float4 av = *reinterpret_cast<const float4*>(
          reinterpret_cast<const float*>(Ap) + (size_t)arow * K + kk + lk);
      a0 = av.x; a1 = av.y; a2 = av.z; a3 = av.w;
    } else {
      const ushort4 av = *reinterpret_cast<const ushort4*>(
          reinterpret_cast<const unsigned short*>(Ap) + (size_t)arow * K + kk + lk);
      a0 = bf2f(av.x); a1 = bf2f(av.y); a2 = bf2f(av.z); a3 = bf2f(av.w);
    }
    if constexpr (LNF) {
      const float4 w4 = *reinterpret_cast<const float4*>(lnw + kk + lk);
      const float4 b4 = *reinterpret_cast<const float4*>(lnb + kk + lk);
      a0 = (a0 - lnm) * lnr * w4.x + b4.x;
      a1 = (a1 - lnm) * lnr * w4.y + b4.y;
      a2 = (a2 - lnm) * lnr * w4.z + b4.z;
      a3 = (a3 - lnm) * lnr * w4.w + b4.w;
    }
    As[lk + 0][lr] = a0;
    As[lk + 1][lr] = a1;
    As[lk + 2][lr] = a2;
    As[lk + 3][lr] = a3;
    const float4 bv = *reinterpret_cast<const float4*>(Bw + (size_t)(kk + br) * N + bn + bc);
    Bs[br][bc + 0] = bv.x;
    Bs[br][bc + 1] = bv.y;
    Bs[br][bc + 2] = bv.z;
    Bs[br][bc + 3] = bv.w;
    __syncthreads();
    #pragma unroll
    for (int k = 0; k < 16; ++k) {
      const float4 a4 = *reinterpret_cast<const float4*>(&As[k][ty * 4]);
      const float4 b4 = *reinterpret_cast<const float4*>(&Bs[k][tx * 4]);
      const float aa[4] = {a4.x, a4.y, a4.z, a4.w};
      const float bb[4] = {b4.x, b4.y, b4.z, b4.w};
      #pragma unroll
      for (int i = 0; i < 4; ++i)
        #pragma unroll
        for (int j = 0; j < 4; ++j)
          acc[i][j] += aa[i] * bb[j];
    }
    __syncthreads();
  }

  const int n0 = bn + tx * 4;
  const float4 bias4 = *reinterpret_cast<const float4*>(bias + n0);
  const float bbv[4] = {bias4.x, bias4.y, bias4.z, bias4.w};

  #pragma unroll
  for (int i = 0; i < 4; ++i) {
    const int m = bm + ty * 4 + i;
    if constexpr (EPI == 0) {
      ushort4 o;
      o.x = f2bf(acc[i][0] + bbv[0]);
      o.y = f2bf(acc[i][1] + bbv[1]);
      o.z = f2bf(acc[i][2] + bbv[2]);
      o.w = f2bf(acc[i][3] + bbv[3]);
      *reinterpret_cast<ushort4*>(
          reinterpret_cast<unsigned short*>(outp) + (size_t)m * N + n0) = o;
    } else if constexpr (EPI == 1) {
      const float4 r4 = *reinterpret_cast<const float4*>(
          reinterpret_cast<const float*>(resp) + (size_t)m * N + n0);
      ushort4 o;
      o.x = f2bf(acc[i][0] + bbv[0] + r4.x);
      o.y = f2bf(acc[i][1] + bbv[1] + r4.y);
      o.z = f2bf(acc[i][2] + bbv[2] + r4.z);
      o.w = f2bf(acc[i][3] + bbv[3] + r4.w);
      *reinterpret_cast<ushort4*>(
          reinterpret_cast<unsigned short*>(outp) + (size_t)m * N + n0) = o;
    } else if constexpr (EPI == 2) {
      ushort4 o;
      unsigned short* op = &o.x;
      #pragma unroll
      for (int j = 0; j < 4; ++j) {
        const float u = acc[i][j] + bbv[j];
        op[j] = f2bf(0.5f * u * (1.0f + erff(u * 0.70710678118654752f)));
      }
      *reinterpret_cast<ushort4*>(
          reinterpret_cast<unsigned short*>(outp) + (size_t)m * N + n0) = o;
    } else {  // EPI == 3: f32 NCHW scatter, +bias +res(bf16)
      const ushort4 r4 = *reinterpret_cast<const ushort4*>(
          reinterpret_cast<const unsigned short*>(resp) + (size_t)m * 256 + n0);
      const float rr[4] = {bf2f(r4.x), bf2f(r4.y), bf2f(r4.z), bf2f(r4.w)};
      const int mg = row0 + m;
      const int b  = mg / HW;
      const int sp = mg - b * HW;
      float* og = reinterpret_cast<float*>(outp) + (size_t)b * 256 * HW + sp;
      #pragma unroll
      for (int j = 0; j < 4; ++j)
        og[(size_t)(n0 + j) * HW] = acc[i][j] + bbv[j] + rr[j];
    }
  }
}

// ------------- Kernel 4: windowed attention (one chunk = NB batches) ------------
// qkv: bf16 (MCH, 768) chunk-local token rows.  outD: bf16 (MCH, 256).
__global__ __launch_bounds__(256) void attn_kernel(const unsigned short* __restrict__ qkv,
    const float* __restrict__ rpb, unsigned short* __restrict__ outD)
{
  __shared__ float Qs[49][33];
  __shared__ float Ks[49][33];
  __shared__ float Vs[49][33];
  __shared__ float S[49][50];
  const int tid  = threadIdx.x;
  const int head = blockIdx.x & 7;
  const int bn   = blockIdx.x >> 3;     // b_local*64 + di*8 + dj
  const int b    = bn >> 6;             // 0..NB-1 (chunk-local)
  const int di   = (bn >> 3) & 7;
  const int dj   = bn & 7;

  for (int idx = tid; idx < 49 * 32; idx += 256) {
    const int n = idx >> 5, d = idx & 31;
    const int li = n / 7, lj = n - (n / 7) * 7;
    const size_t t = (size_t)b * HW + (li * 8 + di) * Ww + (lj * 8 + dj);
    const unsigned short* row = qkv + t * 768 + head * 32 + d;
    Qs[n][d] = bf2f(row[0]) * 0.17677669529663689f;
    Ks[n][d] = bf2f(row[256]);
    Vs[n][d] = bf2f(row[512]);
  }
  __syncthreads();

  for (int idx = tid; idx < 49 * 49; idx += 256) {
    const int n = idx / 49, m = idx - (idx / 49) * 49;
    float acc = 0.f;
    #pragma unroll
    for (int d = 0; d < 32; ++d) acc += Qs[n][d] * Ks[m][d];
    const int dI = n / 7 - m / 7 + 6;
    const int dJ = (n % 7) - (m % 7) + 6;
    acc += rpb[(dI * 13 + dJ) * 8 + head];
    S[n][m] = acc;
  }
  __syncthreads();

  const int wv = tid >> 6, lane = tid & 63;
  for (int n = wv; n < 49; n += 4) {
    float v = (lane < 49) ? S[n][lane] : -3.4e38f;
    float mx = v;
    #pragma unroll
    for (int o = 32; o >= 1; o >>= 1) mx = fmaxf(mx, __shfl_xor(mx, o));
    float p = (lane < 49) ? expf(v - mx) : 0.f;
    float sm = p;
    #pragma unroll
    for (int o = 32; o >= 1; o >>= 1) sm += __shfl_xor(sm, o);
    if (lane < 49) S[n][lane] = p / sm;
  }
  __syncthreads();

  for (int idx = tid; idx < 49 * 32; idx += 256) {
    const int n = idx >> 5, d = idx & 31;
    float acc = 0.f;
    #pragma unroll
    for (int m = 0; m < 49; ++m) acc += S[n][m] * Vs[m][d];
    const int li = n / 7, lj = n - (n / 7) * 7;
    const size_t t = (size_t)b * HW + (li * 8 + di) * Ww + (lj * 8 + dj);
    outD[t * 256 + head * 32 + d] = f2bf(acc);
  }
}

// ------------------------------- launcher --------------------------------------
extern "C" void kernel_launch(void* const* d_in, const int* in_sizes, int n_in,
                              void* d_out, int out_size, void* d_ws, size_t ws_size,
                              hipStream_t stream) {
  (void)in_sizes; (void)n_in; (void)out_size; (void)ws_size;
  const float* x      = (const float*)d_in[0];
  const float* cpe_w  = (const float*)d_in[1];
  const float* cpe_b  = (const float*)d_in[2];
  const float* ln1_w  = (const float*)d_in[3];
  const float* ln1_b  = (const float*)d_in[4];
  const float* rpb    = (const float*)d_in[5];
  const float* qkv_w  = (const float*)d_in[6];
  const float* qkv_b  = (const float*)d_in[7];
  const float* proj_w = (const float*)d_in[8];
  const float* proj_b = (const float*)d_in[9];
  const float* ln2_w  = (const float*)d_in[10];
  const float* ln2_b  = (const float*)d_in[11];
  const float* fc1_w  = (const float*)d_in[12];
  const float* fc1_b  = (const float*)d_in[13];
  const float* fc2_w  = (const float*)d_in[14];
  const float* fc2_b  = (const float*)d_in[15];

  // Workspace layout (75.0 MB total):
  //   mu1[T] f32 @0, rs1[T] @401408, mu2[T] @802816, rs2[T] @1204224
  //   slot1 (QKV chunk 38.5MB / H1 chunk 51.4MB, shared) @1605632
  //   slot2 (D chunk bf16 12.8MB) @52985856
  //   slot3 (E chunk bf16 12.8MB) @65830912   -> end 78675968
  char* ws = (char*)d_ws;
  float* mu1 = (float*)(ws);
  float* rs1 = (float*)(ws + 401408);
  float* mu2 = (float*)(ws + 802816);
  float* rs2 = (float*)(ws + 1204224);
  unsigned short* slot1 = (unsigned short*)(ws + 1605632);
  unsigned short* Dbuf  = (unsigned short*)(ws + 52985856);
  unsigned short* Ebuf  = (unsigned short*)(ws + 65830912);
  float* Abuf = (float*)d_out;   // shortcut lives in d_out until final write

  // 1. CPE depthwise conv + residual -> token layout shortcut A (in d_out)
  cpe_kernel<<<Tn, 256, 0, stream>>>(x, cpe_w, cpe_b, Abuf);
  // 2. LN1 stats (full T)
  stats_kernel<0><<<Tn / 4, 256, 0, stream>>>(Abuf, mu1, rs1);

  for (int c = 0; c < NCHUNK; ++c) {
    const int r0 = c * MCH;
    const float* Ac = Abuf + (size_t)r0 * Cc;
    // 3. QKV GEMM (LN1 fused): (MCH,256)@(256,768) -> bf16 slot1
    gemm_kernel<0, 1, 0><<<dim3(MCH / 64, 12), 256, 0, stream>>>(
        Ac, qkv_w, qkv_b, ln1_w, ln1_b, mu1 + r0, rs1 + r0, nullptr, slot1, 256, 768, r0);
    // 4. windowed attention -> D chunk (bf16)
    attn_kernel<<<NB * 64 * 8, 256, 0, stream>>>(slot1, rpb, Dbuf);
    // 5. proj GEMM + bias + shortcut(f32) -> E chunk (bf16)
    gemm_kernel<1, 0, 1><<<dim3(MCH / 64, 4), 256, 0, stream>>>(
        Dbuf, proj_w, proj_b, nullptr, nullptr, nullptr, nullptr, Ac, Ebuf, 256, 256, r0);
    // 6. LN2 stats on E chunk
    stats_kernel<1><<<MCH / 4, 256, 0, stream>>>(Ebuf, mu2 + r0, rs2 + r0);
    // 7. FC1 + GELU (LN2 fused) -> bf16 H1 (slot1, QKV dead)
    gemm_kernel<1, 1, 2><<<dim3(MCH / 64, 16), 256, 0, stream>>>(
        Ebuf, fc1_w, fc1_b, ln2_w, ln2_b, mu2 + r0, rs2 + r0, nullptr, slot1, 256, 1024, r0);
    // 8. FC2 + bias + residual(E bf16) -> NCHW output (overwrites A rows of this chunk only)
    gemm_kernel<1, 0, 3><<<dim3(MCH / 64, 4), 256, 0, stream>>>(
        slot1, fc2_w, fc2_b, nullptr, nullptr, nullptr, nullptr, Ebuf, d_out, 1024, 256, r0);
  }
}

// Round 3
// 1118.802 us; speedup vs baseline: 3.4168x; 3.4168x over previous
//
#include <hip/hip_runtime.h>
#include <hip/hip_bf16.h>

#define DEVINL __device__ __forceinline__

constexpr int Cc  = 256;
constexpr int Hh  = 56;
constexpr int Ww  = 56;
constexpr int Tn  = 32 * 56 * 56;   // 100352 tokens
constexpr int HW  = Hh * Ww;        // 3136
constexpr int NB  = 8;              // batches per chunk
constexpr int NCHUNK = 32 / NB;     // 4 chunks
constexpr int MCH = NB * HW;        // 25088 rows per chunk

typedef __attribute__((ext_vector_type(4))) float f32x4;
typedef __attribute__((ext_vector_type(8))) short bf16x8;

DEVINL unsigned short f2bf(float f) {
  __hip_bfloat16 h = __float2bfloat16(f);
  return *reinterpret_cast<unsigned short*>(&h);
}
DEVINL float bf2f(unsigned short u) {
  union { unsigned int i; float f; } v; v.i = (unsigned int)u << 16; return v.f;
}

#define GLOAD_LDS16(gp, lp) \
  __builtin_amdgcn_global_load_lds((const __attribute__((address_space(1))) void*)(gp), \
                                   (__attribute__((address_space(3))) void*)(lp), 16, 0, 0)

// ------------- Kernel 1: depthwise 3x3 CPE + residual, NCHW -> token(t,c) f32 ---
// block = (b, 8-row tile, 16-channel group); LDS-staged haloed slab, coalesced.
__global__ __launch_bounds__(256) void cpe_kernel(const float* __restrict__ x,
    const float* __restrict__ cw, const float* __restrict__ cb,
    float* __restrict__ out)
{
  __shared__ float Xs[16 * 10 * 58];
  const int tid = threadIdx.x;
  const int bx  = blockIdx.x;
  const int cg  = bx & 15;
  const int t2  = bx >> 4;
  const int hg  = t2 % 7;
  const int b   = t2 / 7;
  const int c0  = cg * 16;
  const int h0  = hg * 8;

  for (int idx = tid; idx < 16 * 10 * 58; idx += 256) {
    const int ci  = idx / 580;
    const int rem = idx - ci * 580;
    const int rr  = rem / 58;
    const int wc  = rem - rr * 58;
    const int h2  = h0 - 1 + rr;
    const int w2  = wc - 1;
    float v = 0.f;
    if (h2 >= 0 && h2 < Hh && w2 >= 0 && w2 < Ww)
      v = x[((size_t)(b * Cc + c0 + ci)) * HW + h2 * Ww + w2];
    Xs[idx] = v;
  }
  __syncthreads();

  #pragma unroll 4
  for (int it = 0; it < 28; ++it) {
    const int oidx = it * 256 + tid;
    const int ci  = oidx & 15;
    const int tok = oidx >> 4;
    const int hr  = tok / 56;
    const int w   = tok - hr * 56;
    const float* Xc  = Xs + ci * 580;
    const float* cwc = cw + (size_t)(c0 + ci) * 9;
    float acc = Xc[(hr + 1) * 58 + (w + 1)];     // residual (center x)
    #pragma unroll
    for (int dh = 0; dh < 3; ++dh)
      #pragma unroll
      for (int dw = 0; dw < 3; ++dw)
        acc += cwc[dh * 3 + dw] * Xc[(hr + dh) * 58 + (w + dw)];
    out[((size_t)(b * HW + (h0 + hr) * Ww + w)) * Cc + c0 + ci] = acc + cb[c0 + ci];
  }
}

// ------------- Kernel 2: fused LN stats+apply -> bf16 row (wave per token) -----
template<int BF>
__global__ __launch_bounds__(256) void ln_apply(const void* __restrict__ inp,
    const float* __restrict__ w, const float* __restrict__ b,
    unsigned short* __restrict__ out)
{
  const int lane = threadIdx.x & 63;
  const size_t t = (size_t)blockIdx.x * 4 + (threadIdx.x >> 6);
  float v0, v1, v2, v3;
  if constexpr (BF == 0) {
    const float4 v = *reinterpret_cast<const float4*>(
        reinterpret_cast<const float*>(inp) + t * Cc + lane * 4);
    v0 = v.x; v1 = v.y; v2 = v.z; v3 = v.w;
  } else {
    const ushort4 v = *reinterpret_cast<const ushort4*>(
        reinterpret_cast<const unsigned short*>(inp) + t * Cc + lane * 4);
    v0 = bf2f(v.x); v1 = bf2f(v.y); v2 = bf2f(v.z); v3 = bf2f(v.w);
  }
  float s  = v0 + v1 + v2 + v3;
  float sq = v0 * v0 + v1 * v1 + v2 * v2 + v3 * v3;
  #pragma unroll
  for (int o = 32; o >= 1; o >>= 1) {
    s  += __shfl_xor(s, o);
    sq += __shfl_xor(sq, o);
  }
  const float mean = s * (1.0f / Cc);
  const float var  = sq * (1.0f / Cc) - mean * mean;
  const float r    = rsqrtf(var + 1e-5f);
  const float4 w4 = *reinterpret_cast<const float4*>(w + lane * 4);
  const float4 b4 = *reinterpret_cast<const float4*>(b + lane * 4);
  ushort4 o;
  o.x = f2bf((v0 - mean) * r * w4.x + b4.x);
  o.y = f2bf((v1 - mean) * r * w4.y + b4.y);
  o.z = f2bf((v2 - mean) * r * w4.z + b4.z);
  o.w = f2bf((v3 - mean) * r * w4.w + b4.w);
  *reinterpret_cast<ushort4*>(out + t * Cc + lane * 4) = o;
}

// ------------- Kernel 3: weight convert+transpose f32[K][N] -> bf16 Wt[N][K] ----
__global__ __launch_bounds__(256) void wconv_kernel(const float* __restrict__ W,
    unsigned short* __restrict__ Wt, int K, int N)
{
  const int q   = blockIdx.x * 256 + threadIdx.x;
  const int nk4 = K >> 2;
  const int n   = q / nk4;
  const int k0  = (q - n * nk4) << 2;
  ushort4 o;
  o.x = f2bf(W[(size_t)(k0 + 0) * N + n]);
  o.y = f2bf(W[(size_t)(k0 + 1) * N + n]);
  o.z = f2bf(W[(size_t)(k0 + 2) * N + n]);
  o.w = f2bf(W[(size_t)(k0 + 3) * N + n]);
  *reinterpret_cast<ushort4*>(Wt + (size_t)n * K + k0) = o;
}

// ------------- MFMA bf16 GEMM: C[M,N] = A[M,K] @ Bt[N,K]^T + epilogue ----------
// m97 structure: 128x128 tile, BK=64, 4 waves (2x2 quadrants of 64x64),
// global_load_lds width-16 staging, 2-barrier loop, 16x16x32 bf16 MFMA.
// EPI 0: bf16 out +bias                       (QKV)
// EPI 1: bf16 out +bias +res(f32,[M][256])    (proj + shortcut)
// EPI 2: bf16 out +bias, exact GELU           (fc1)
// EPI 3: f32 NCHW out +bias +res(bf16,[M][256]) (fc2 + residual + transpose)
template<int EPI>
__global__ __launch_bounds__(256) void mfma_gemm(
    const unsigned short* __restrict__ A, const unsigned short* __restrict__ Bt,
    const float* __restrict__ bias, const void* __restrict__ resp,
    void* __restrict__ outp, int K, int N, int row0)
{
  __shared__ unsigned short Asm[128 * 64];
  __shared__ unsigned short Bsm[128 * 64];
  const int tid  = threadIdx.x;
  const int lane = tid & 63;
  const int wid  = tid >> 6;
  const int wr   = wid >> 1;
  const int wc   = wid & 1;
  const int bm   = blockIdx.x * 128;
  const int bn   = blockIdx.y * 128;

  f32x4 acc[4][4] = {};   // [fm][fn], each 16x16 fragment (4 f32/lane)

  // staging geometry: chunk = 1024 B = 8 rows x 128 B; wave stages 4 A + 4 B chunks
  const int srow = (lane >> 3);        // row within 8-row chunk
  const int skc  = (lane & 7) * 8;     // k element offset (16B granules)

  for (int k0 = 0; k0 < K; k0 += 64) {
    #pragma unroll
    for (int i = 0; i < 4; ++i) {
      const int ch  = wid * 4 + i;
      const int row = ch * 8 + srow;
      GLOAD_LDS16(A  + (size_t)(bm + row) * K + k0 + skc, &Asm[ch * 512]);
      GLOAD_LDS16(Bt + (size_t)(bn + row) * K + k0 + skc, &Bsm[ch * 512]);
    }
    __syncthreads();

    #pragma unroll
    for (int k32 = 0; k32 < 2; ++k32) {
      const int koff = k32 * 32 + (lane >> 4) * 8;
      bf16x8 af[4], bv[4];
      #pragma unroll
      for (int f = 0; f < 4; ++f) {
        af[f] = *reinterpret_cast<const bf16x8*>(
            &Asm[(wr * 64 + f * 16 + (lane & 15)) * 64 + koff]);
        bv[f] = *reinterpret_cast<const bf16x8*>(
            &Bsm[(wc * 64 + f * 16 + (lane & 15)) * 64 + koff]);
      }
      #pragma unroll
      for (int fm = 0; fm < 4; ++fm)
        #pragma unroll
        for (int fn = 0; fn < 4; ++fn)
          acc[fm][fn] = __builtin_amdgcn_mfma_f32_16x16x32_bf16(
              af[fm], bv[fn], acc[fm][fn], 0, 0, 0);
    }
    __syncthreads();
  }

  // epilogue: C/D layout col=lane&15, row=(lane>>4)*4+reg
  const int lr4 = (lane >> 4) * 4;
  const int lc  = lane & 15;
  #pragma unroll
  for (int fn = 0; fn < 4; ++fn) {
    const int gcol = bn + wc * 64 + fn * 16 + lc;
    const float bvs = bias[gcol];
    #pragma unroll
    for (int fm = 0; fm < 4; ++fm) {
      const int rbase = bm + wr * 64 + fm * 16 + lr4;
      #pragma unroll
      for (int r = 0; r < 4; ++r) {
        const int grow = rbase + r;
        float v = acc[fm][fn][r] + bvs;
        if constexpr (EPI == 0) {
          ((unsigned short*)outp)[(size_t)grow * N + gcol] = f2bf(v);
        } else if constexpr (EPI == 1) {
          v += ((const float*)resp)[(size_t)grow * 256 + gcol];
          ((unsigned short*)outp)[(size_t)grow * N + gcol] = f2bf(v);
        } else if constexpr (EPI == 2) {
          v = 0.5f * v * (1.0f + erff(v * 0.70710678118654752f));
          ((unsigned short*)outp)[(size_t)grow * N + gcol] = f2bf(v);
        } else {
          v += bf2f(((const unsigned short*)resp)[(size_t)grow * 256 + gcol]);
          const int mg = row0 + grow;
          const int b  = mg / HW;
          const int sp = mg - b * HW;
          ((float*)outp)[((size_t)b * 256 + gcol) * HW + sp] = v;
        }
      }
    }
  }
}

// ------------- Kernel 5: windowed attention (one chunk = NB batches) ------------
__global__ __launch_bounds__(256) void attn_kernel(const unsigned short* __restrict__ qkv,
    const float* __restrict__ rpb, unsigned short* __restrict__ outD)
{
  __shared__ float Qs[49][33];
  __shared__ float Ks[49][33];
  __shared__ float Vs[49][33];
  __shared__ float S[49][50];
  const int tid  = threadIdx.x;
  const int head = blockIdx.x & 7;
  const int bn   = blockIdx.x >> 3;     // b_local*64 + di*8 + dj
  const int b    = bn >> 6;
  const int di   = (bn >> 3) & 7;
  const int dj   = bn & 7;

  for (int idx = tid; idx < 49 * 32; idx += 256) {
    const int n = idx >> 5, d = idx & 31;
    const int li = n / 7, lj = n - (n / 7) * 7;
    const size_t t = (size_t)b * HW + (li * 8 + di) * Ww + (lj * 8 + dj);
    const unsigned short* row = qkv + t * 768 + head * 32 + d;
    Qs[n][d] = bf2f(row[0]) * 0.17677669529663689f;
    Ks[n][d] = bf2f(row[256]);
    Vs[n][d] = bf2f(row[512]);
  }
  __syncthreads();

  for (int idx = tid; idx < 49 * 49; idx += 256) {
    const int n = idx / 49, m = idx - (idx / 49) * 49;
    float acc = 0.f;
    #pragma unroll
    for (int d = 0; d < 32; ++d) acc += Qs[n][d] * Ks[m][d];
    const int dI = n / 7 - m / 7 + 6;
    const int dJ = (n % 7) - (m % 7) + 6;
    acc += rpb[(dI * 13 + dJ) * 8 + head];
    S[n][m] = acc;
  }
  __syncthreads();

  const int wv = tid >> 6, lane = tid & 63;
  for (int n = wv; n < 49; n += 4) {
    float v = (lane < 49) ? S[n][lane] : -3.4e38f;
    float mx = v;
    #pragma unroll
    for (int o = 32; o >= 1; o >>= 1) mx = fmaxf(mx, __shfl_xor(mx, o));
    float p = (lane < 49) ? expf(v - mx) : 0.f;
    float sm = p;
    #pragma unroll
    for (int o = 32; o >= 1; o >>= 1) sm += __shfl_xor(sm, o);
    if (lane < 49) S[n][lane] = p / sm;
  }
  __syncthreads();

  for (int idx = tid; idx < 49 * 32; idx += 256) {
    const int n = idx >> 5, d = idx & 31;
    float acc = 0.f;
    #pragma unroll
    for (int m = 0; m < 49; ++m) acc += S[n][m] * Vs[m][d];
    const int li = n / 7, lj = n - (n / 7) * 7;
    const size_t t = (size_t)b * HW + (li * 8 + di) * Ww + (lj * 8 + dj);
    outD[t * 256 + head * 32 + d] = f2bf(acc);
  }
}

// ------------------------------- launcher --------------------------------------
extern "C" void kernel_launch(void* const* d_in, const int* in_sizes, int n_in,
                              void* d_out, int out_size, void* d_ws, size_t ws_size,
                              hipStream_t stream) {
  (void)in_sizes; (void)n_in; (void)out_size; (void)ws_size;
  const float* x      = (const float*)d_in[0];
  const float* cpe_w  = (const float*)d_in[1];
  const float* cpe_b  = (const float*)d_in[2];
  const float* ln1_w  = (const float*)d_in[3];
  const float* ln1_b  = (const float*)d_in[4];
  const float* rpb    = (const float*)d_in[5];
  const float* qkv_w  = (const float*)d_in[6];
  const float* qkv_b  = (const float*)d_in[7];
  const float* proj_w = (const float*)d_in[8];
  const float* proj_b = (const float*)d_in[9];
  const float* ln2_w  = (const float*)d_in[10];
  const float* ln2_b  = (const float*)d_in[11];
  const float* fc1_w  = (const float*)d_in[12];
  const float* fc1_b  = (const float*)d_in[13];
  const float* fc2_w  = (const float*)d_in[14];
  const float* fc2_b  = (const float*)d_in[15];

  // Workspace layout (75.0 MB):
  //   qkv_wt @0 (393216) | proj_wt @393216 (131072) | fc1_wt @524288 (524288)
  //   fc2_wt @1048576 (524288)
  //   slotX (A1/D/G bf16 chunk, 12.85MB) @1572864
  //   slotQ (QKV 38.5MB / H1 51.4MB)     @14417920
  //   slotE (E bf16 chunk, 12.85MB)      @65798144  -> end 78643200
  char* ws = (char*)d_ws;
  unsigned short* qkv_wt  = (unsigned short*)(ws);
  unsigned short* proj_wt = (unsigned short*)(ws + 393216);
  unsigned short* fc1_wt  = (unsigned short*)(ws + 524288);
  unsigned short* fc2_wt  = (unsigned short*)(ws + 1048576);
  unsigned short* slotX   = (unsigned short*)(ws + 1572864);
  unsigned short* slotQ   = (unsigned short*)(ws + 14417920);
  unsigned short* slotE   = (unsigned short*)(ws + 65798144);
  float* Abuf = (float*)d_out;   // f32 shortcut lives in d_out until final write

  // 0. weight convert + transpose (bf16, [N][K])
  wconv_kernel<<<192, 256, 0, stream>>>(qkv_w,  qkv_wt,  256, 768);
  wconv_kernel<<<64,  256, 0, stream>>>(proj_w, proj_wt, 256, 256);
  wconv_kernel<<<256, 256, 0, stream>>>(fc1_w,  fc1_wt,  256, 1024);
  wconv_kernel<<<256, 256, 0, stream>>>(fc2_w,  fc2_wt,  1024, 256);

  // 1. CPE depthwise conv + residual -> token-layout shortcut A (in d_out)
  cpe_kernel<<<32 * 7 * 16, 256, 0, stream>>>(x, cpe_w, cpe_b, Abuf);

  for (int c = 0; c < NCHUNK; ++c) {
    const int r0 = c * MCH;
    const float* Ac = Abuf + (size_t)r0 * Cc;
    // 2. LN1 apply -> bf16 A1 (slotX)
    ln_apply<0><<<MCH / 4, 256, 0, stream>>>(Ac, ln1_w, ln1_b, slotX);
    // 3. QKV GEMM -> bf16 slotQ
    mfma_gemm<0><<<dim3(MCH / 128, 6), 256, 0, stream>>>(
        slotX, qkv_wt, qkv_b, nullptr, slotQ, 256, 768, r0);
    // 4. windowed attention -> D (overwrites A1 in slotX)
    attn_kernel<<<NB * 64 * 8, 256, 0, stream>>>(slotQ, rpb, slotX);
    // 5. proj GEMM + bias + shortcut(f32 A) -> E (slotE)
    mfma_gemm<1><<<dim3(MCH / 128, 2), 256, 0, stream>>>(
        slotX, proj_wt, proj_b, Ac, slotE, 256, 256, r0);
    // 6. LN2 apply -> bf16 G (overwrites D in slotX)
    ln_apply<1><<<MCH / 4, 256, 0, stream>>>(slotE, ln2_w, ln2_b, slotX);
    // 7. FC1 + GELU -> bf16 H1 (slotQ)
    mfma_gemm<2><<<dim3(MCH / 128, 8), 256, 0, stream>>>(
        slotX, fc1_wt, fc1_b, nullptr, slotQ, 256, 1024, r0);
    // 8. FC2 + bias + residual(E) -> f32 NCHW output
    mfma_gemm<3><<<dim3(MCH / 128, 2), 256, 0, stream>>>(
        slotQ, fc2_wt, fc2_b, slotE, d_out, 1024, 256, r0);
  }
}

// Round 4
// 854.337 us; speedup vs baseline: 4.4745x; 1.3096x over previous
//
#include <hip/hip_runtime.h>
#include <hip/hip_bf16.h>

#define DEVINL __device__ __forceinline__

constexpr int Cc  = 256;
constexpr int Hh  = 56;
constexpr int Ww  = 56;
constexpr int HW  = Hh * Ww;        // 3136
constexpr int NB  = 8;              // batches per chunk
constexpr int NCHUNK = 32 / NB;     // 4 chunks
constexpr int MCH = NB * HW;        // 25088 rows per chunk
constexpr float SCALEF = 0.17677669529663689f;  // 32^-0.5

typedef __attribute__((ext_vector_type(4))) float f32x4;
typedef __attribute__((ext_vector_type(8))) short bf16x8;

DEVINL unsigned short f2bf(float f) {
  __hip_bfloat16 h = __float2bfloat16(f);
  return *reinterpret_cast<unsigned short*>(&h);
}
DEVINL float bf2f(unsigned short u) {
  union { unsigned int i; float f; } v; v.i = (unsigned int)u << 16; return v.f;
}

#define GLOAD_LDS16(gp, lp) \
  __builtin_amdgcn_global_load_lds((const __attribute__((address_space(1))) void*)(gp), \
                                   (__attribute__((address_space(3))) void*)(lp), 16, 0, 0)

// ------------- Kernel 1: depthwise 3x3 CPE + residual, NCHW -> token(t,c) f32 ---
// channel slab stride 581 (581 mod 32 = 5, odd) -> conflict-free compute reads.
__global__ __launch_bounds__(256) void cpe_kernel(const float* __restrict__ x,
    const float* __restrict__ cw, const float* __restrict__ cb,
    float* __restrict__ out)
{
  __shared__ float Xs[16 * 581];
  const int tid = threadIdx.x;
  const int bx  = blockIdx.x;
  const int cg  = bx & 15;
  const int t2  = bx >> 4;
  const int hg  = t2 % 7;
  const int b   = t2 / 7;
  const int c0  = cg * 16;
  const int h0  = hg * 8;

  for (int idx = tid; idx < 16 * 580; idx += 256) {
    const int ci  = idx / 580;
    const int rem = idx - ci * 580;
    const int rr  = rem / 58;
    const int wc  = rem - rr * 58;
    const int h2  = h0 - 1 + rr;
    const int w2  = wc - 1;
    float v = 0.f;
    if (h2 >= 0 && h2 < Hh && w2 >= 0 && w2 < Ww)
      v = x[((size_t)(b * Cc + c0 + ci)) * HW + h2 * Ww + w2];
    Xs[ci * 581 + rem] = v;
  }
  __syncthreads();

  #pragma unroll 4
  for (int it = 0; it < 28; ++it) {
    const int oidx = it * 256 + tid;
    const int ci  = oidx & 15;
    const int tok = oidx >> 4;
    const int hr  = tok / 56;
    const int w   = tok - hr * 56;
    const float* Xc  = Xs + ci * 581;
    const float* cwc = cw + (size_t)(c0 + ci) * 9;
    float acc = Xc[(hr + 1) * 58 + (w + 1)];     // residual (center x)
    #pragma unroll
    for (int dh = 0; dh < 3; ++dh)
      #pragma unroll
      for (int dw = 0; dw < 3; ++dw)
        acc += cwc[dh * 3 + dw] * Xc[(hr + dh) * 58 + (w + dw)];
    out[((size_t)(b * HW + (h0 + hr) * Ww + w)) * Cc + c0 + ci] = acc + cb[c0 + ci];
  }
}

// ------------- Kernel 2: fused LN stats+apply -> bf16 row (wave per token) -----
template<int BF>
__global__ __launch_bounds__(256) void ln_apply(const void* __restrict__ inp,
    const float* __restrict__ w, const float* __restrict__ b,
    unsigned short* __restrict__ out)
{
  const int lane = threadIdx.x & 63;
  const size_t t = (size_t)blockIdx.x * 4 + (threadIdx.x >> 6);
  float v0, v1, v2, v3;
  if constexpr (BF == 0) {
    const float4 v = *reinterpret_cast<const float4*>(
        reinterpret_cast<const float*>(inp) + t * Cc + lane * 4);
    v0 = v.x; v1 = v.y; v2 = v.z; v3 = v.w;
  } else {
    const ushort4 v = *reinterpret_cast<const ushort4*>(
        reinterpret_cast<const unsigned short*>(inp) + t * Cc + lane * 4);
    v0 = bf2f(v.x); v1 = bf2f(v.y); v2 = bf2f(v.z); v3 = bf2f(v.w);
  }
  float s  = v0 + v1 + v2 + v3;
  float sq = v0 * v0 + v1 * v1 + v2 * v2 + v3 * v3;
  #pragma unroll
  for (int o = 32; o >= 1; o >>= 1) {
    s  += __shfl_xor(s, o);
    sq += __shfl_xor(sq, o);
  }
  const float mean = s * (1.0f / Cc);
  const float var  = sq * (1.0f / Cc) - mean * mean;
  const float r    = rsqrtf(var + 1e-5f);
  const float4 w4 = *reinterpret_cast<const float4*>(w + lane * 4);
  const float4 b4 = *reinterpret_cast<const float4*>(b + lane * 4);
  ushort4 o;
  o.x = f2bf((v0 - mean) * r * w4.x + b4.x);
  o.y = f2bf((v1 - mean) * r * w4.y + b4.y);
  o.z = f2bf((v2 - mean) * r * w4.z + b4.z);
  o.w = f2bf((v3 - mean) * r * w4.w + b4.w);
  *reinterpret_cast<ushort4*>(out + t * Cc + lane * 4) = o;
}

// ------------- Kernel 3: tiled weight transpose f32[K][N] -> bf16 Wt[N][K] -----
// QS: scale rows n<256 (folds q*SCALE into Q weights for qkv).
template<int QS>
__global__ __launch_bounds__(256) void wconv_kernel(const float* __restrict__ W,
    unsigned short* __restrict__ Wt, int K, int N)
{
  __shared__ float Xs[32][33];
  const int kb = blockIdx.x * 32, nb = blockIdx.y * 32;
  const int tn = threadIdx.x & 31, tk = threadIdx.x >> 5;
  #pragma unroll
  for (int i = 0; i < 4; ++i)
    Xs[tk + i * 8][tn] = W[(size_t)(kb + tk + i * 8) * N + nb + tn];
  __syncthreads();
  const int wk = threadIdx.x & 31, wn = threadIdx.x >> 5;
  #pragma unroll
  for (int i = 0; i < 4; ++i) {
    const int n = nb + wn + i * 8;
    float s = (QS && n < 256) ? SCALEF : 1.0f;
    Wt[(size_t)n * K + kb + wk] = f2bf(Xs[wk][wn + i * 8] * s);
  }
}

// ------------- Kernel 4: padded rel-pos bias table Bias[8][64][64] f32 ----------
__global__ __launch_bounds__(256) void biasgen_kernel(const float* __restrict__ rpb,
    float* __restrict__ biasT)
{
  const int i = blockIdx.x * 256 + threadIdx.x;   // 32768 total
  const int h = i >> 12, n = (i >> 6) & 63, m = i & 63;
  float v;
  if (m >= 49) {
    v = -1e30f;
  } else {
    const int nc = n < 49 ? n : 48;
    const int dI = nc / 7 - m / 7 + 6;
    const int dJ = nc % 7 - m % 7 + 6;
    v = rpb[(dI * 13 + dJ) * 8 + h];
  }
  biasT[i] = v;
}

// ------------- MFMA bf16 GEMM: C[M,N] = A[M,K] @ Bt[N,K]^T + epilogue ----------
// EPI 0: bf16 out +bias (QS: bias[n<256]*=SCALE)   (QKV)
// EPI 1: bf16 out +bias +res(f32,[M][256])         (proj + shortcut)
// EPI 2: bf16 out +bias, exact GELU                (fc1)
// EPI 3: f32 NCHW out +bias +res(bf16,[M][256])    (fc2 + residual + transpose)
template<int EPI, int QS>
__global__ __launch_bounds__(256) void mfma_gemm(
    const unsigned short* __restrict__ A, const unsigned short* __restrict__ Bt,
    const float* __restrict__ bias, const void* __restrict__ resp,
    void* __restrict__ outp, int K, int N, int row0)
{
  __shared__ unsigned short Asm[128 * 64];
  __shared__ unsigned short Bsm[128 * 64];
  const int tid  = threadIdx.x;
  const int lane = tid & 63;
  const int wid  = tid >> 6;
  const int wr   = wid >> 1;
  const int wc   = wid & 1;
  const int bm   = blockIdx.x * 128;
  const int bn   = blockIdx.y * 128;

  f32x4 acc[4][4] = {};

  const int srow = (lane >> 3);
  const int skc  = (lane & 7) * 8;

  for (int k0 = 0; k0 < K; k0 += 64) {
    #pragma unroll
    for (int i = 0; i < 4; ++i) {
      const int ch  = wid * 4 + i;
      const int row = ch * 8 + srow;
      GLOAD_LDS16(A  + (size_t)(bm + row) * K + k0 + skc, &Asm[ch * 512]);
      GLOAD_LDS16(Bt + (size_t)(bn + row) * K + k0 + skc, &Bsm[ch * 512]);
    }
    __syncthreads();

    #pragma unroll
    for (int k32 = 0; k32 < 2; ++k32) {
      const int koff = k32 * 32 + (lane >> 4) * 8;
      bf16x8 af[4], bv[4];
      #pragma unroll
      for (int f = 0; f < 4; ++f) {
        af[f] = *reinterpret_cast<const bf16x8*>(
            &Asm[(wr * 64 + f * 16 + (lane & 15)) * 64 + koff]);
        bv[f] = *reinterpret_cast<const bf16x8*>(
            &Bsm[(wc * 64 + f * 16 + (lane & 15)) * 64 + koff]);
      }
      #pragma unroll
      for (int fm = 0; fm < 4; ++fm)
        #pragma unroll
        for (int fn = 0; fn < 4; ++fn)
          acc[fm][fn] = __builtin_amdgcn_mfma_f32_16x16x32_bf16(
              af[fm], bv[fn], acc[fm][fn], 0, 0, 0);
    }
    __syncthreads();
  }

  const int lr4 = (lane >> 4) * 4;
  const int lc  = lane & 15;
  #pragma unroll
  for (int fn = 0; fn < 4; ++fn) {
    const int gcol = bn + wc * 64 + fn * 16 + lc;
    float bvs = bias[gcol];
    if constexpr (QS) { if (gcol < 256) bvs *= SCALEF; }
    #pragma unroll
    for (int fm = 0; fm < 4; ++fm) {
      const int rbase = bm + wr * 64 + fm * 16 + lr4;
      #pragma unroll
      for (int r = 0; r < 4; ++r) {
        const int grow = rbase + r;
        float v = acc[fm][fn][r] + bvs;
        if constexpr (EPI == 0) {
          ((unsigned short*)outp)[(size_t)grow * N + gcol] = f2bf(v);
        } else if constexpr (EPI == 1) {
          v += ((const float*)resp)[(size_t)grow * 256 + gcol];
          ((unsigned short*)outp)[(size_t)grow * N + gcol] = f2bf(v);
        } else if constexpr (EPI == 2) {
          v = 0.5f * v * (1.0f + erff(v * 0.70710678118654752f));
          ((unsigned short*)outp)[(size_t)grow * N + gcol] = f2bf(v);
        } else {
          v += bf2f(((const unsigned short*)resp)[(size_t)grow * 256 + gcol]);
          const int mg = row0 + grow;
          const int b  = mg / HW;
          const int sp = mg - b * HW;
          ((float*)outp)[((size_t)b * 256 + gcol) * HW + sp] = v;
        }
      }
    }
  }
}

// ------------- Kernel 5: MFMA windowed attention, one block per window ----------
// 4 waves x 2 heads each, zero barriers (per-wave private LDS regions).
// Per-wave LDS (14848 B): Q[64x32] stride 80B @0, K @5120, Vt[32x64] stride 144B
// @10240; P[64x64] stride 144B overlays Q+K after S is consumed.
__global__ __launch_bounds__(256) void attn_mfma(const unsigned short* __restrict__ qkv,
    const float* __restrict__ biasT, unsigned short* __restrict__ outD)
{
  __shared__ char smem[4 * 14848];
  const int tid  = threadIdx.x;
  const int lane = tid & 63;
  const int wid  = tid >> 6;
  char* base = smem + wid * 14848;
  char* Qs = base;
  char* Ks = base + 5120;
  char* Vt = base + 10240;
  char* Ps = base;                      // overlays Q+K

  const int blk = blockIdx.x;           // b*64 + di*8 + dj
  const int b   = blk >> 6;
  const int di  = (blk >> 3) & 7;
  const int dj  = blk & 7;
  const size_t t00 = (size_t)b * HW + di * Ww + dj;

  const int lg = lane >> 4;             // 4-lane-group id (0..3)
  const int lc = lane & 15;

  for (int rep = 0; rep < 2; ++rep) {
    const int h = wid * 2 + rep;

    // zero full per-wave region (covers pad rows 49..63 and P residue)
    for (int i = lane; i < 1856; i += 64)
      reinterpret_cast<unsigned long long*>(base)[i] = 0ull;

    // stage Q,K rows (49 x 32 bf16, 8B granules)
    for (int idx = lane; idx < 392; idx += 64) {
      const int row = idx >> 3, dq = idx & 7;
      const int li = row / 7, lj = row - (row / 7) * 7;
      const size_t t = t00 + (size_t)(li * 8) * Ww + lj * 8;
      const unsigned short* src = qkv + t * 768 + h * 32 + dq * 4;
      *reinterpret_cast<uint2*>(Qs + row * 80 + dq * 8) =
          *reinterpret_cast<const uint2*>(src);
      *reinterpret_cast<uint2*>(Ks + row * 80 + dq * 8) =
          *reinterpret_cast<const uint2*>(src + 256);
    }
    // stage V transposed: Vt[d][k=token]
    for (int idx = lane; idx < 784; idx += 64) {
      const int row = idx >> 4, q = idx & 15;
      const int li = row / 7, lj = row - (row / 7) * 7;
      const size_t t = t00 + (size_t)(li * 8) * Ww + lj * 8;
      const unsigned int v = *reinterpret_cast<const unsigned int*>(
          qkv + t * 768 + h * 32 + 512 + q * 2);
      *reinterpret_cast<unsigned short*>(Vt + (2 * q) * 144 + row * 2) =
          (unsigned short)(v & 0xffff);
      *reinterpret_cast<unsigned short*>(Vt + (2 * q + 1) * 144 + row * 2) =
          (unsigned short)(v >> 16);
    }

    // S = Q K^T  (Q pre-scaled via weights); 4x4 tiles of 16x16, K=32
    f32x4 sacc[4][4] = {};
    {
      bf16x8 af[4], bv[4];
      #pragma unroll
      for (int f = 0; f < 4; ++f) {
        af[f] = *reinterpret_cast<const bf16x8*>(Qs + (f * 16 + lc) * 80 + lg * 16);
        bv[f] = *reinterpret_cast<const bf16x8*>(Ks + (f * 16 + lc) * 80 + lg * 16);
      }
      #pragma unroll
      for (int fm = 0; fm < 4; ++fm)
        #pragma unroll
        for (int fn = 0; fn < 4; ++fn)
          sacc[fm][fn] = __builtin_amdgcn_mfma_f32_16x16x32_bf16(
              af[fm], bv[fn], sacc[fm][fn], 0, 0, 0);
    }

    // softmax rows (C/D layout: col = lc, row = fm*16 + lg*4 + r) + bias
    const float* bh = biasT + h * 4096;
    #pragma unroll
    for (int fm = 0; fm < 4; ++fm) {
      float rowv[4][4];     // [r][fn]
      #pragma unroll
      for (int r = 0; r < 4; ++r) {
        const int n = fm * 16 + lg * 4 + r;
        #pragma unroll
        for (int fn = 0; fn < 4; ++fn)
          rowv[r][fn] = sacc[fm][fn][r] + bh[n * 64 + fn * 16 + lc];
      }
      #pragma unroll
      for (int r = 0; r < 4; ++r) {
        float mx = fmaxf(fmaxf(rowv[r][0], rowv[r][1]), fmaxf(rowv[r][2], rowv[r][3]));
        #pragma unroll
        for (int o = 8; o >= 1; o >>= 1) mx = fmaxf(mx, __shfl_xor(mx, o));
        float p[4], sm = 0.f;
        #pragma unroll
        for (int fn = 0; fn < 4; ++fn) { p[fn] = __expf(rowv[r][fn] - mx); sm += p[fn]; }
        #pragma unroll
        for (int o = 8; o >= 1; o >>= 1) sm += __shfl_xor(sm, o);
        const float inv = 1.0f / sm;
        const int n = fm * 16 + lg * 4 + r;
        #pragma unroll
        for (int fn = 0; fn < 4; ++fn)
          *reinterpret_cast<unsigned short*>(Ps + n * 144 + (fn * 16 + lc) * 2) =
              f2bf(p[fn] * inv);
      }
    }

    // O = P V : M 4x16, N 2x16, K = 64 (2 steps)
    f32x4 oacc[4][2] = {};
    #pragma unroll
    for (int ks = 0; ks < 2; ++ks) {
      bf16x8 pa[4], vb[2];
      #pragma unroll
      for (int fm = 0; fm < 4; ++fm)
        pa[fm] = *reinterpret_cast<const bf16x8*>(
            Ps + (fm * 16 + lc) * 144 + ks * 64 + lg * 16);
      #pragma unroll
      for (int fn = 0; fn < 2; ++fn)
        vb[fn] = *reinterpret_cast<const bf16x8*>(
            Vt + (fn * 16 + lc) * 144 + ks * 64 + lg * 16);
      #pragma unroll
      for (int fm = 0; fm < 4; ++fm)
        #pragma unroll
        for (int fn = 0; fn < 2; ++fn)
          oacc[fm][fn] = __builtin_amdgcn_mfma_f32_16x16x32_bf16(
              pa[fm], vb[fn], oacc[fm][fn], 0, 0, 0);
    }

    // store O rows n<49 to token layout
    #pragma unroll
    for (int fm = 0; fm < 4; ++fm) {
      #pragma unroll
      for (int r = 0; r < 4; ++r) {
        const int n = fm * 16 + lg * 4 + r;
        if (n < 49) {
          const int li = n / 7, lj = n - (n / 7) * 7;
          const size_t t = t00 + (size_t)(li * 8) * Ww + lj * 8;
          outD[t * 256 + h * 32 + lc]      = f2bf(oacc[fm][0][r]);
          outD[t * 256 + h * 32 + 16 + lc] = f2bf(oacc[fm][1][r]);
        }
      }
    }
  }
}

// ------------------------------- launcher --------------------------------------
extern "C" void kernel_launch(void* const* d_in, const int* in_sizes, int n_in,
                              void* d_out, int out_size, void* d_ws, size_t ws_size,
                              hipStream_t stream) {
  (void)in_sizes; (void)n_in; (void)out_size; (void)ws_size;
  const float* x      = (const float*)d_in[0];
  const float* cpe_w  = (const float*)d_in[1];
  const float* cpe_b  = (const float*)d_in[2];
  const float* ln1_w  = (const float*)d_in[3];
  const float* ln1_b  = (const float*)d_in[4];
  const float* rpb    = (const float*)d_in[5];
  const float* qkv_w  = (const float*)d_in[6];
  const float* qkv_b  = (const float*)d_in[7];
  const float* proj_w = (const float*)d_in[8];
  const float* proj_b = (const float*)d_in[9];
  const float* ln2_w  = (const float*)d_in[10];
  const float* ln2_b  = (const float*)d_in[11];
  const float* fc1_w  = (const float*)d_in[12];
  const float* fc1_b  = (const float*)d_in[13];
  const float* fc2_w  = (const float*)d_in[14];
  const float* fc2_b  = (const float*)d_in[15];

  // Workspace layout (identical extents to the proven 78,643,200 B):
  //   qkv_wt @0 | proj_wt @393216 | fc1_wt @524288 | fc2_wt @1048576
  //   slotX @1572864 (12.85MB) | slotQ @14417920 (51.4MB) | slotE @65798144 (12.85MB)
  //   biasT (128KB, per-chunk transient) lives at the start of slotE.
  char* ws = (char*)d_ws;
  unsigned short* qkv_wt  = (unsigned short*)(ws);
  unsigned short* proj_wt = (unsigned short*)(ws + 393216);
  unsigned short* fc1_wt  = (unsigned short*)(ws + 524288);
  unsigned short* fc2_wt  = (unsigned short*)(ws + 1048576);
  unsigned short* slotX   = (unsigned short*)(ws + 1572864);
  unsigned short* slotQ   = (unsigned short*)(ws + 14417920);
  unsigned short* slotE   = (unsigned short*)(ws + 65798144);
  float*          biasT   = (float*)slotE;
  float* Abuf = (float*)d_out;   // f32 shortcut lives in d_out until final write

  // 0. weight transposes (bf16 [N][K]); qkv Q-rows pre-scaled by SCALE
  wconv_kernel<1><<<dim3(8, 24),  256, 0, stream>>>(qkv_w,  qkv_wt,  256, 768);
  wconv_kernel<0><<<dim3(8, 8),   256, 0, stream>>>(proj_w, proj_wt, 256, 256);
  wconv_kernel<0><<<dim3(8, 32),  256, 0, stream>>>(fc1_w,  fc1_wt,  256, 1024);
  wconv_kernel<0><<<dim3(32, 8),  256, 0, stream>>>(fc2_w,  fc2_wt,  1024, 256);

  // 1. CPE depthwise conv + residual -> token-layout shortcut A (in d_out)
  cpe_kernel<<<32 * 7 * 16, 256, 0, stream>>>(x, cpe_w, cpe_b, Abuf);

  for (int c = 0; c < NCHUNK; ++c) {
    const int r0 = c * MCH;
    const float* Ac = Abuf + (size_t)r0 * Cc;
    // 2. LN1 apply -> bf16 A1 (slotX)
    ln_apply<0><<<MCH / 4, 256, 0, stream>>>(Ac, ln1_w, ln1_b, slotX);
    // 3. QKV GEMM -> bf16 slotQ (bias Q-part scaled in epilogue)
    mfma_gemm<0, 1><<<dim3(MCH / 128, 6), 256, 0, stream>>>(
        slotX, qkv_wt, qkv_b, nullptr, slotQ, 256, 768, r0);
    // 3b. bias table (slotE start; E not yet live this chunk)
    biasgen_kernel<<<128, 256, 0, stream>>>(rpb, biasT);
    // 4. MFMA windowed attention -> D (overwrites A1 in slotX)
    attn_mfma<<<NB * 64, 256, 0, stream>>>(slotQ, biasT, slotX);
    // 5. proj GEMM + bias + shortcut(f32 A) -> E (slotE; overwrites biasT)
    mfma_gemm<1, 0><<<dim3(MCH / 128, 2), 256, 0, stream>>>(
        slotX, proj_wt, proj_b, Ac, slotE, 256, 256, r0);
    // 6. LN2 apply -> bf16 G (overwrites D in slotX)
    ln_apply<1><<<MCH / 4, 256, 0, stream>>>(slotE, ln2_w, ln2_b, slotX);
    // 7. FC1 + GELU -> bf16 H1 (slotQ)
    mfma_gemm<2, 0><<<dim3(MCH / 128, 8), 256, 0, stream>>>(
        slotX, fc1_wt, fc1_b, nullptr, slotQ, 256, 1024, r0);
    // 8. FC2 + bias + residual(E) -> f32 NCHW output
    mfma_gemm<3, 0><<<dim3(MCH / 128, 2), 256, 0, stream>>>(
        slotQ, fc2_wt, fc2_b, slotE, d_out, 1024, 256, r0);
  }
}